// Round 4
// baseline (244.640 us; speedup 1.0000x reference)
//
#include <hip/hip_runtime.h>
#include <math.h>

#define Bb 4
#define Hh 128
#define Ww 256
#define Cc 64
#define Ff 128
#define INH 130   // H+2
#define INW 258   // W+2

#define WSLOT 72   // shorts per column (64 + 8 pad): 144B stride, 16B-aligned
#define WCOLS 132  // cols 0..130 = data window, col 131 = dedicated zero column

typedef __attribute__((ext_vector_type(8))) __bf16 bf16x8;
typedef __attribute__((ext_vector_type(4))) float floatx4;

// ---------------------------------------------------------------------------
// Prep: transpose conv kernel [576][128] f32 -> kT[128][576] bf16 (native cvt).
// ---------------------------------------------------------------------------
__global__ void prep_kernel(const float* __restrict__ kmat,
                            unsigned short* __restrict__ kT) {
  int gid = blockIdx.x * 256 + threadIdx.x;
  if (gid < 576 * 128) {
    int f = gid & 127;        // f contiguous in source -> coalesced reads
    int k = gid >> 7;
    __bf16 v = (__bf16)kmat[gid];
    kT[f * 576 + k] = __builtin_bit_cast(unsigned short, v);
  }
}

// ---------------------------------------------------------------------------
// Fused: per (b,h,128-w tile). Per tap:
//   fill: premix column window (bilinear collapses to 4 block-uniform weights
//         x contiguous column loads; 132 cols x 4 chunks of 16ch = 528 tasks)
//   stage lB: B-tile from L2-resident kT (B from global per-tap was round 3's
//         regression: 295MB kTp traffic thrashed L2, FETCH/WRITE x4)
//   MFMA: A-frags + B-frags both pure ds_read_b128.
// ---------------------------------------------------------------------------
__global__ __launch_bounds__(256, 4) void fused_kernel(
    const float* __restrict__ in, const float* __restrict__ bias,
    const unsigned short* __restrict__ kT, const float* __restrict__ offtab,
    float* __restrict__ out) {
  __shared__ unsigned short winH[WCOLS * WSLOT];
  __shared__ unsigned short lB[128 * WSLOT];

  // XCD swizzle: each XCD gets one b and a contiguous h-range (~4.4MB == L2)
  int lidx = ((blockIdx.x & 7) << 7) | (blockIdx.x >> 3);
  int wt = lidx & 1;
  int h  = (lidx >> 1) & 127;
  int b  = lidx >> 8;
  int w0 = wt << 7;

  int tid  = threadIdx.x;
  int lane = tid & 63;
  int wave = tid >> 6;
  int m_base = (wave >> 1) << 6;
  int n_base = (wave & 1) << 6;
  int l15  = lane & 15;
  int quad = lane >> 4;

  floatx4 acc[4][4];
#pragma unroll
  for (int i = 0; i < 4; i++)
#pragma unroll
    for (int j = 0; j < 4; j++) acc[i][j] = (floatx4){0.f, 0.f, 0.f, 0.f};

  const float* inb = in + (size_t)b * Hh * Ww * Cc;

  for (int tap = 0; tap < 9; tap++) {
    float off0 = offtab[(h * 9 + tap) * 2 + 0];
    float off1 = offtab[(h * 9 + tap) * 2 + 1];
    float dyk = (float)(tap / 3), dxk = (float)(tap % 3);

    // ---- y side (block-uniform): rows + weights, pad folded into weights ----
    float y = (float)h + dyk + off0;
    y = fminf(fmaxf(y, 0.f), (float)(INH - 1));
    int y0i = (int)floorf(y);
    int y1i = y0i + 1;
    y0i = min(max(y0i, 0), INH - 1);
    y1i = min(max(y1i, 0), INH - 1);
    float wy0 = (float)y1i - y;
    float wy1 = y - (float)y0i;
    if (!(y0i >= 1 && y0i <= Hh)) wy0 = 0.f;
    if (!(y1i >= 1 && y1i <= Hh)) wy1 = 0.f;
    const float* row0 = inb + (size_t)min(max(y0i - 1, 0), Hh - 1) * Ww * Cc;
    const float* row1 = inb + (size_t)min(max(y1i - 1, 0), Hh - 1) * Ww * Cc;

    // ---- x side: block-uniform fractional weights + window base ----
    float xrep = (float)w0 + dxk + off1;
    float flo  = floorf(xrep);
    int jb = (int)flo - 1;
    float fr = xrep - flo;
    float q00 = wy0 * (1.f - fr), q01 = wy0 * fr;
    float q10 = wy1 * (1.f - fr), q11 = wy1 * fr;

    // ---- per-lane slots for this tap (faithful ref op order) ----
    int slotv[4];
#pragma unroll
    for (int mi = 0; mi < 4; mi++) {
      int w = m_base + mi * 16 + l15;
      float x = (float)(w0 + w) + dxk + off1;
      if (x < 0.f) x += (float)INW;
      if (x > (float)(INW - 1)) x -= (float)INW;
      int x0i = (int)floorf(x);
      int s = x0i - jb;
      if (s < 0) s += INW;
      if (s > 131) s = 131;
      slotv[mi] = s;
    }

    // ---- fill: 132 cols x 4 chunks of 16ch = 528 tasks; batched loads ----
#pragma unroll
    for (int it = 0; it < 3; it++) {
      int task = tid + (it << 8);
      if (task < WCOLS * 4) {
        int j   = task >> 2;
        int c16 = (task & 3) << 4;
        int col = jb + j;
        if (col < 0) col += INW;
        if (col > INW - 1) col -= INW;
        int ncol = jb + j + 1;
        if (ncol < 0) ncol += INW;
        if (ncol > INW - 1) ncol -= INW;
        bool cok = (col >= 1) & (col <= Ww) & (j < 131);
        bool nok = (ncol >= 1) & (ncol <= Ww) & (j < 131);
        int ci = min(max(col - 1, 0), Ww - 1);
        int nx = min(max(ncol - 1, 0), Ww - 1);
        float w00 = cok ? q00 : 0.f, w01 = nok ? q01 : 0.f;
        float w10 = cok ? q10 : 0.f, w11 = nok ? q11 : 0.f;
        const float* p0 = row0 + ci * Cc + c16;
        const float* p1 = row0 + nx * Cc + c16;
        const float* p2 = row1 + ci * Cc + c16;
        const float* p3 = row1 + nx * Cc + c16;
        bf16x8 o0, o1;
#pragma unroll
        for (int q = 0; q < 4; q++) {
          float4 a0 = *(const float4*)(p0 + 4 * q);
          float4 a1 = *(const float4*)(p1 + 4 * q);
          float4 b0 = *(const float4*)(p2 + 4 * q);
          float4 b1 = *(const float4*)(p3 + 4 * q);
          float px = w00 * a0.x + w01 * a1.x + w10 * b0.x + w11 * b1.x;
          float py = w00 * a0.y + w01 * a1.y + w10 * b0.y + w11 * b1.y;
          float pz = w00 * a0.z + w01 * a1.z + w10 * b0.z + w11 * b1.z;
          float pw = w00 * a0.w + w01 * a1.w + w10 * b0.w + w11 * b1.w;
          if (q < 2) {
            o0[q * 4 + 0] = (__bf16)px; o0[q * 4 + 1] = (__bf16)py;
            o0[q * 4 + 2] = (__bf16)pz; o0[q * 4 + 3] = (__bf16)pw;
          } else {
            o1[(q - 2) * 4 + 0] = (__bf16)px; o1[(q - 2) * 4 + 1] = (__bf16)py;
            o1[(q - 2) * 4 + 2] = (__bf16)pz; o1[(q - 2) * 4 + 3] = (__bf16)pw;
          }
        }
        *(bf16x8*)&winH[j * WSLOT + c16]     = o0;
        *(bf16x8*)&winH[j * WSLOT + c16 + 8] = o1;
      }
    }

    // ---- stage B tile: kT[f][tap*64..+64] -> lB (L2-resident source) ----
    {
      int f = tid >> 1, seg = tid & 1;
      const unsigned short* src = kT + f * 576 + tap * 64 + seg * 32;
      unsigned short* dst = &lB[f * WSLOT + seg * 32];
#pragma unroll
      for (int i = 0; i < 4; i++)
        *(uint4*)(dst + i * 8) = *(const uint4*)(src + i * 8);
    }

    __syncthreads();

    // ---- MFMA: A-frags from window, B-frags from lB; all ds_read_b128 ----
#pragma unroll
    for (int kk = 0; kk < 2; kk++) {
      bf16x8 afrag[4], bfrag[4];
#pragma unroll
      for (int mi = 0; mi < 4; mi++)
        afrag[mi] = *(const bf16x8*)&winH[slotv[mi] * WSLOT + kk * 32 + quad * 8];
#pragma unroll
      for (int ni = 0; ni < 4; ni++)
        bfrag[ni] = *(const bf16x8*)&lB[(n_base + ni * 16 + l15) * WSLOT + kk * 32 + quad * 8];
#pragma unroll
      for (int mi = 0; mi < 4; mi++)
#pragma unroll
        for (int ni = 0; ni < 4; ni++)
          acc[mi][ni] = __builtin_amdgcn_mfma_f32_16x16x32_bf16(
              afrag[mi], bfrag[ni], acc[mi][ni], 0, 0, 0);
    }
    __syncthreads();
  }

  // ---- epilogue: bias + relu (C/D: col=lane&15, row=quad*4+r) ----
  size_t outbase = ((size_t)(b * Hh + h) * Ww + w0);
#pragma unroll
  for (int ni = 0; ni < 4; ni++) {
    int f = n_base + ni * 16 + l15;
    float bv = bias[f];
#pragma unroll
    for (int mi = 0; mi < 4; mi++) {
#pragma unroll
      for (int r = 0; r < 4; r++) {
        int m = m_base + mi * 16 + quad * 4 + r;
        out[(outbase + m) * Ff + f] = fmaxf(acc[mi][ni][r] + bv, 0.f);
      }
    }
  }
}

// ---------------------------------------------------------------------------
// Host-side fp64 offset table (faithful numpy port; fp64 required: fp32 flips
// the ux>0 branch at h=0 where cos(pi/2)~6e-17 -> half-width x shift).
// ---------------------------------------------------------------------------
static float h_off[Hh * 9 * 2];

static void compute_offsets_host() {
  const double pi = 3.14159265358979323846;
  double unit_w = 2.0 * pi / (double)Ww;
  double unit_h = pi / (2.0 * (double)Hh);
  double rho = tan(unit_w);
  double theta = ((double)(Ww / 2) - 0.5 * (double)Ww) * unit_w;
  static const int r0t[9] = {1, 1, 1, 0, 0, 0, -1, -1, -1};
  static const int r1t[9] = {-1, 0, 1, -1, 0, 1, -1, 0, 1};
  for (int h = 0; h < Hh; h++) {
    double phi = ((double)Hh - (double)h) * unit_h;
    double cph = cos(phi), sph = sin(phi);
    double cth = cos(theta), sth = sin(theta);
    double pux = cph * cth, puy = sph, puz = cph * sth;
    double txx = puz, txy = 0.0, txz = -pux;
    double tyx = puy * txz - puz * txy;
    double tyy = puz * txx - pux * txz;
    double tyz = pux * txy - puy * txx;
    double xr[10], yr[10];
    for (int p = 0; p < 10; p++) {
      int r0 = (p == 9) ? 0 : r0t[p];
      int r1 = (p == 9) ? 0 : r1t[p];
      double ux = pux + rho * ((double)r0 * txx + (double)r1 * tyx);
      double uy = puy + rho * ((double)r0 * txy + (double)r1 * tyy);
      double uz = puz + rho * ((double)r0 * txz + (double)r1 * tyz);
      double base = atan2(uz, ux);
      double th;
      if (ux > 0.0)        th = base;
      else if (ux < 0.0)   th = (uz >= 0.0) ? base + pi : base - pi;
      else                 th = (uz > 0.0) ? pi * 0.5 : -pi * 0.5;
      double ph = asin(uy);
      xr[p] = (th / pi + 1.0) * 0.5 * (double)Ww;
      yr[p] = (1.0 - 2.0 * ph / pi) * (double)Hh;
    }
    for (int j = 0; j < 9; j++) {
      h_off[(h * 9 + j) * 2 + 0] = (float)(xr[j] - xr[9]);  // added to y (faithful swap)
      h_off[(h * 9 + j) * 2 + 1] = (float)(yr[j] - yr[9]);  // added to x
    }
  }
}

extern "C" void kernel_launch(void* const* d_in, const int* in_sizes, int n_in,
                              void* d_out, int out_size, void* d_ws, size_t ws_size,
                              hipStream_t stream) {
  const float* in   = (const float*)d_in[0];
  const float* kmat = (const float*)d_in[1];
  const float* bias = (const float*)d_in[2];
  float* out = (float*)d_out;

  // ws layout: offtab (9216 B) | kT (128x576 bf16 = 147456 B)
  float* offtab = (float*)d_ws;
  unsigned short* kT = (unsigned short*)((char*)d_ws + Hh * 9 * 2 * sizeof(float));
  if (ws_size < (size_t)(Hh * 9 * 2 * sizeof(float) + 128 * 576 * sizeof(unsigned short)))
    return;

  compute_offsets_host();
  hipMemcpyAsync(offtab, h_off, sizeof(h_off), hipMemcpyHostToDevice, stream);
  prep_kernel<<<288, 256, 0, stream>>>(kmat, kT);
  fused_kernel<<<Bb * Hh * (Ww / 128), 256, 0, stream>>>(in, bias, kT, offtab, out);
}

// Round 5
// 169.262 us; speedup vs baseline: 1.4453x; 1.4453x over previous
//
#include <hip/hip_runtime.h>
#include <math.h>

#define Bb 4
#define Hh 128
#define Ww 256
#define Cc 64
#define Ff 128
#define INH 130   // H+2
#define INW 258   // W+2

#define WSLOT 72   // shorts per column (64 + 8 pad): 144B stride, 16B-aligned
#define WCOLS 132  // cols 0..130 = data window, col 131 = dedicated zero column

typedef __attribute__((ext_vector_type(8))) __bf16 bf16x8;
typedef __attribute__((ext_vector_type(4))) __bf16 bf16x4;
typedef __attribute__((ext_vector_type(4))) float floatx4;

// ---------------------------------------------------------------------------
// Prep: transpose conv kernel [576][128] f32 -> kT[128][576] bf16 (native cvt).
// ---------------------------------------------------------------------------
__global__ void prep_kernel(const float* __restrict__ kmat,
                            unsigned short* __restrict__ kT) {
  int gid = blockIdx.x * 256 + threadIdx.x;
  if (gid < 576 * 128) {
    int f = gid & 127;        // f contiguous in source -> coalesced reads
    int k = gid >> 7;
    __bf16 v = (__bf16)kmat[gid];
    kT[f * 576 + k] = __builtin_bit_cast(unsigned short, v);
  }
}

// ---------------------------------------------------------------------------
// Fused: per (b,h,128-w tile). Per tap:
//   fill: premix column window. One column x 16ch per thread (528 tasks,
//         address/mask calc once per thread), but SECTOR-ALIGNED lane map:
//         for load q, lanes 0-3 read column j's bytes [q*64, q*64+64)
//         contiguously -> every global load = 16 full 64B sectors.
//         (Rounds 3/4 regression: 16B-per-lane @ 64B stride -> partial-sector
//          requests + L1 thrash -> FETCH/WRITE x4. Round 2 was sector-aligned.)
//   stage lB: B-tile from L2-resident kT.
//   MFMA: A-frags + B-frags both pure ds_read_b128.
// ---------------------------------------------------------------------------
__global__ __launch_bounds__(256, 4) void fused_kernel(
    const float* __restrict__ in, const float* __restrict__ bias,
    const unsigned short* __restrict__ kT, const float* __restrict__ offtab,
    float* __restrict__ out) {
  __shared__ unsigned short winH[WCOLS * WSLOT];
  __shared__ unsigned short lB[128 * WSLOT];

  // XCD swizzle: each XCD gets one b and a contiguous h-range (~4.4MB == L2)
  int lidx = ((blockIdx.x & 7) << 7) | (blockIdx.x >> 3);
  int wt = lidx & 1;
  int h  = (lidx >> 1) & 127;
  int b  = lidx >> 8;
  int w0 = wt << 7;

  int tid  = threadIdx.x;
  int lane = tid & 63;
  int wave = tid >> 6;
  int m_base = (wave >> 1) << 6;
  int n_base = (wave & 1) << 6;
  int l15  = lane & 15;
  int quad = lane >> 4;

  floatx4 acc[4][4];
#pragma unroll
  for (int i = 0; i < 4; i++)
#pragma unroll
    for (int j = 0; j < 4; j++) acc[i][j] = (floatx4){0.f, 0.f, 0.f, 0.f};

  const float* inb = in + (size_t)b * Hh * Ww * Cc;

  for (int tap = 0; tap < 9; tap++) {
    float off0 = offtab[(h * 9 + tap) * 2 + 0];
    float off1 = offtab[(h * 9 + tap) * 2 + 1];
    float dyk = (float)(tap / 3), dxk = (float)(tap % 3);

    // ---- y side (block-uniform): rows + weights, pad folded into weights ----
    float y = (float)h + dyk + off0;
    y = fminf(fmaxf(y, 0.f), (float)(INH - 1));
    int y0i = (int)floorf(y);
    int y1i = y0i + 1;
    y0i = min(max(y0i, 0), INH - 1);
    y1i = min(max(y1i, 0), INH - 1);
    float wy0 = (float)y1i - y;
    float wy1 = y - (float)y0i;
    if (!(y0i >= 1 && y0i <= Hh)) wy0 = 0.f;
    if (!(y1i >= 1 && y1i <= Hh)) wy1 = 0.f;
    const float* row0 = inb + (size_t)min(max(y0i - 1, 0), Hh - 1) * Ww * Cc;
    const float* row1 = inb + (size_t)min(max(y1i - 1, 0), Hh - 1) * Ww * Cc;

    // ---- x side: block-uniform fractional weights + window base ----
    float xrep = (float)w0 + dxk + off1;
    float flo  = floorf(xrep);
    int jb = (int)flo - 1;
    float fr = xrep - flo;
    float q00 = wy0 * (1.f - fr), q01 = wy0 * fr;
    float q10 = wy1 * (1.f - fr), q11 = wy1 * fr;

    // ---- per-lane slots for this tap (faithful ref op order) ----
    int slotv[4];
#pragma unroll
    for (int mi = 0; mi < 4; mi++) {
      int w = m_base + mi * 16 + l15;
      float x = (float)(w0 + w) + dxk + off1;
      if (x < 0.f) x += (float)INW;
      if (x > (float)(INW - 1)) x -= (float)INW;
      int x0i = (int)floorf(x);
      int s = x0i - jb;
      if (s < 0) s += INW;
      if (s > 131) s = 131;
      slotv[mi] = s;
    }

    // ---- fill: 132 cols x 4 lane-chunks = 528 tasks; sector-aligned ----
#pragma unroll
    for (int it = 0; it < 3; it++) {
      int task = tid + (it << 8);
      if (task < WCOLS * 4) {
        int j   = task >> 2;
        int c4f = (task & 3) << 2;   // float offset of this lane inside a 16-ch q-group
        int col = jb + j;
        if (col < 0) col += INW;
        if (col > INW - 1) col -= INW;
        int ncol = jb + j + 1;
        if (ncol < 0) ncol += INW;
        if (ncol > INW - 1) ncol -= INW;
        bool cok = (col >= 1) & (col <= Ww) & (j < 131);
        bool nok = (ncol >= 1) & (ncol <= Ww) & (j < 131);
        int ci = min(max(col - 1, 0), Ww - 1);
        int nx = min(max(ncol - 1, 0), Ww - 1);
        float w00 = cok ? q00 : 0.f, w01 = nok ? q01 : 0.f;
        float w10 = cok ? q10 : 0.f, w11 = nok ? q11 : 0.f;
        const float* p0 = row0 + ci * Cc + c4f;
        const float* p1 = row0 + nx * Cc + c4f;
        const float* p2 = row1 + ci * Cc + c4f;
        const float* p3 = row1 + nx * Cc + c4f;
#pragma unroll
        for (int q = 0; q < 4; q++) {
          // channels q*16 + c4f + 0..3 ; lanes 0-3 of a quad read 64B contig
          float4 a0 = *(const float4*)(p0 + q * 16);
          float4 a1 = *(const float4*)(p1 + q * 16);
          float4 b0 = *(const float4*)(p2 + q * 16);
          float4 b1 = *(const float4*)(p3 + q * 16);
          float px = w00 * a0.x + w01 * a1.x + w10 * b0.x + w11 * b1.x;
          float py = w00 * a0.y + w01 * a1.y + w10 * b0.y + w11 * b1.y;
          float pz = w00 * a0.z + w01 * a1.z + w10 * b0.z + w11 * b1.z;
          float pw = w00 * a0.w + w01 * a1.w + w10 * b0.w + w11 * b1.w;
          bf16x4 o;
          o[0] = (__bf16)px; o[1] = (__bf16)py;
          o[2] = (__bf16)pz; o[3] = (__bf16)pw;
          *(bf16x4*)&winH[j * WSLOT + q * 16 + c4f] = o;   // 8B ds_write_b64
        }
      }
    }

    // ---- stage B tile: kT[f][tap*64..+64] -> lB (L2-resident source) ----
    {
      int f = tid >> 1, seg = tid & 1;
      const unsigned short* src = kT + f * 576 + tap * 64 + seg * 32;
      unsigned short* dst = &lB[f * WSLOT + seg * 32];
#pragma unroll
      for (int i = 0; i < 4; i++)
        *(uint4*)(dst + i * 8) = *(const uint4*)(src + i * 8);
    }

    __syncthreads();

    // ---- MFMA: A-frags from window, B-frags from lB; all ds_read_b128 ----
#pragma unroll
    for (int kk = 0; kk < 2; kk++) {
      bf16x8 afrag[4], bfrag[4];
#pragma unroll
      for (int mi = 0; mi < 4; mi++)
        afrag[mi] = *(const bf16x8*)&winH[slotv[mi] * WSLOT + kk * 32 + quad * 8];
#pragma unroll
      for (int ni = 0; ni < 4; ni++)
        bfrag[ni] = *(const bf16x8*)&lB[(n_base + ni * 16 + l15) * WSLOT + kk * 32 + quad * 8];
#pragma unroll
      for (int mi = 0; mi < 4; mi++)
#pragma unroll
        for (int ni = 0; ni < 4; ni++)
          acc[mi][ni] = __builtin_amdgcn_mfma_f32_16x16x32_bf16(
              afrag[mi], bfrag[ni], acc[mi][ni], 0, 0, 0);
    }
    __syncthreads();
  }

  // ---- epilogue: bias + relu (C/D: col=lane&15, row=quad*4+r) ----
  size_t outbase = ((size_t)(b * Hh + h) * Ww + w0);
#pragma unroll
  for (int ni = 0; ni < 4; ni++) {
    int f = n_base + ni * 16 + l15;
    float bv = bias[f];
#pragma unroll
    for (int mi = 0; mi < 4; mi++) {
#pragma unroll
      for (int r = 0; r < 4; r++) {
        int m = m_base + mi * 16 + quad * 4 + r;
        out[(outbase + m) * Ff + f] = fmaxf(acc[mi][ni][r] + bv, 0.f);
      }
    }
  }
}

// ---------------------------------------------------------------------------
// Host-side fp64 offset table (faithful numpy port; fp64 required: fp32 flips
// the ux>0 branch at h=0 where cos(pi/2)~6e-17 -> half-width x shift).
// ---------------------------------------------------------------------------
static float h_off[Hh * 9 * 2];

static void compute_offsets_host() {
  const double pi = 3.14159265358979323846;
  double unit_w = 2.0 * pi / (double)Ww;
  double unit_h = pi / (2.0 * (double)Hh);
  double rho = tan(unit_w);
  double theta = ((double)(Ww / 2) - 0.5 * (double)Ww) * unit_w;
  static const int r0t[9] = {1, 1, 1, 0, 0, 0, -1, -1, -1};
  static const int r1t[9] = {-1, 0, 1, -1, 0, 1, -1, 0, 1};
  for (int h = 0; h < Hh; h++) {
    double phi = ((double)Hh - (double)h) * unit_h;
    double cph = cos(phi), sph = sin(phi);
    double cth = cos(theta), sth = sin(theta);
    double pux = cph * cth, puy = sph, puz = cph * sth;
    double txx = puz, txy = 0.0, txz = -pux;
    double tyx = puy * txz - puz * txy;
    double tyy = puz * txx - pux * txz;
    double tyz = pux * txy - puy * txx;
    double xr[10], yr[10];
    for (int p = 0; p < 10; p++) {
      int r0 = (p == 9) ? 0 : r0t[p];
      int r1 = (p == 9) ? 0 : r1t[p];
      double ux = pux + rho * ((double)r0 * txx + (double)r1 * tyx);
      double uy = puy + rho * ((double)r0 * txy + (double)r1 * tyy);
      double uz = puz + rho * ((double)r0 * txz + (double)r1 * tyz);
      double base = atan2(uz, ux);
      double th;
      if (ux > 0.0)        th = base;
      else if (ux < 0.0)   th = (uz >= 0.0) ? base + pi : base - pi;
      else                 th = (uz > 0.0) ? pi * 0.5 : -pi * 0.5;
      double ph = asin(uy);
      xr[p] = (th / pi + 1.0) * 0.5 * (double)Ww;
      yr[p] = (1.0 - 2.0 * ph / pi) * (double)Hh;
    }
    for (int j = 0; j < 9; j++) {
      h_off[(h * 9 + j) * 2 + 0] = (float)(xr[j] - xr[9]);  // added to y (faithful swap)
      h_off[(h * 9 + j) * 2 + 1] = (float)(yr[j] - yr[9]);  // added to x
    }
  }
}

extern "C" void kernel_launch(void* const* d_in, const int* in_sizes, int n_in,
                              void* d_out, int out_size, void* d_ws, size_t ws_size,
                              hipStream_t stream) {
  const float* in   = (const float*)d_in[0];
  const float* kmat = (const float*)d_in[1];
  const float* bias = (const float*)d_in[2];
  float* out = (float*)d_out;

  // ws layout: offtab (9216 B) | kT (128x576 bf16 = 147456 B)
  float* offtab = (float*)d_ws;
  unsigned short* kT = (unsigned short*)((char*)d_ws + Hh * 9 * 2 * sizeof(float));
  if (ws_size < (size_t)(Hh * 9 * 2 * sizeof(float) + 128 * 576 * sizeof(unsigned short)))
    return;

  compute_offsets_host();
  hipMemcpyAsync(offtab, h_off, sizeof(h_off), hipMemcpyHostToDevice, stream);
  prep_kernel<<<288, 256, 0, stream>>>(kmat, kT);
  fused_kernel<<<Bb * Hh * (Ww / 128), 256, 0, stream>>>(in, bias, kT, offtab, out);
}